// Round 7
// baseline (926.211 us; speedup 1.0000x reference)
//
#include <hip/hip_runtime.h>

// phi (B,2,H,W) f32 -> out (B,1,H,W) f32 ; splat ones with bilinear weights, wrap BC.
// Gather formulation, tent weights, multi-row amortization, store-only commit:
//   each wave owns RB=8 output rows x 56 cols; scans RB+6=14 source rows;
//   col tent weights (7 static offsets) computed once per source, reused by all rows;
//   compile-time-pruned (t,m) pairs (row tent == 0 when |t-3-m| >= 4);
//   per-lane register slots, __shfl column routing, ONE PLAIN STORE per output pixel
//   (exclusive ownership -> no atomics, no output memset).
// Sources with |dx|>=3 or |dy|>=3 (P ~ 0.5% for N(0,1)) append (idx,weight) entries
// to a ws list (atomic counter); flush_fallback adds them into out afterwards.
constexpr int H = 2048, W = 2048;
constexpr int HW = H * W;
constexpr int OUTW = 56;                    // output cols per wave (64 lanes - 8 halo)
constexpr int NCH = (W + OUTW - 1) / OUTW;  // 37 col-chunks (last ragged)
constexpr int RB  = 8;                      // owned rows per wave
constexpr int WPB = 4;                      // waves per block
constexpr int ROWSPB = RB * WPB;            // 32 rows per block
constexpr int NSRC = RB + 6;                // scanned source rows per wave

__global__ __launch_bounds__(256)
void splat_gather8(const float* __restrict__ phi, float* __restrict__ out,
                   unsigned* __restrict__ counter, uint2* __restrict__ entries,
                   unsigned capacity) {
    int wid  = threadIdx.x >> 6;
    int lane = threadIdx.x & 63;

    const int rgPerImg = H / ROWSPB;        // 64
    int bid = blockIdx.x;
    int b   = bid / (NCH * rgPerImg);
    int rem = bid - b * (NCH * rgPerImg);
    int c0i = rem / rgPerImg;
    int rg  = rem - c0i * rgPerImg;
    int r0  = rg * ROWSPB + wid * RB;       // first owned row of this wave
    int c0  = c0i * OUTW;

    const float* phiB = phi + (size_t)b * 2 * HW;
    float* outb = out + (size_t)b * HW;

    int scu = c0 - 4 + lane;                // unwrapped source col of this lane
    int scw = scu & (W - 1);                // wrapped col for loads
    bool ownedCol = (lane >= 4) && (lane < 4 + OUTW) && (scu < W);

    // prefetch the NSRC candidate source rows (both displacement planes), coalesced
    float dxv[NSRC], dyv[NSRC];
    #pragma unroll
    for (int t = 0; t < NSRC; ++t) {
        int srow = (r0 + t - 3) & (H - 1);
        dxv[t] = phiB[(size_t)srow * W + scw];
        dyv[t] = phiB[(size_t)HW + (size_t)srow * W + scw];
    }

    float slot[RB][7];
    #pragma unroll
    for (int m = 0; m < RB; ++m)
        #pragma unroll
        for (int k = 0; k < 7; ++k) slot[m][k] = 0.0f;

    #pragma unroll
    for (int t = 0; t < NSRC; ++t) {
        float dx = dxv[t], dy = dyv[t];
        bool valid = (__builtin_fabsf(dx) < 3.0f) && (__builtin_fabsf(dy) < 3.0f);
        float dyM = valid ? dy : 16384.0f;   // invalid -> all col tents 0 -> list only

        // col tent weights toward offsets ko = k-3 (shared across owned rows)
        float ct[7];
        #pragma unroll
        for (int k = 0; k < 7; ++k) {
            float d = dyM - (float)(k - 3);
            ct[k] = __builtin_fmaxf(1.0f - __builtin_fabsf(d), 0.0f);
        }

        // row tents toward owned rows + rank-1 accumulate (pruned: rw==0 if |t-3-m|>=4)
        #pragma unroll
        for (int m = 0; m < RB; ++m) {
            if (t - m < 0 || t - m > 6) continue;   // compile-time DCE under unroll
            float dist = dx + (float)(t - 3 - m);   // x - (r0+m), unwrapped
            float rw = __builtin_fmaxf(1.0f - __builtin_fabsf(dist), 0.0f);
            #pragma unroll
            for (int k = 0; k < 7; ++k)
                slot[m][k] = __builtin_fmaf(rw, ct[k], slot[m][k]);
        }

        // wide-displacement fallback: this wave owns source row r0+(t-3) for t in [3,3+RB)
        if (t >= 3 && t < 3 + RB) {
            if (__any((!valid) && ownedCol)) {
                if ((!valid) && ownedCol) {
                    int srow = (r0 + t - 3) & (H - 1);
                    float x = (float)srow + dx;
                    float y = (float)scw + dy;
                    float x0 = floorf(x), y0 = floorf(y);
                    float wx1 = x - x0, wx0 = 1.0f - wx1;
                    float wy1 = y - y0, wy0 = 1.0f - wy1;
                    unsigned gx0 = ((unsigned)(int)x0) & (H - 1);
                    unsigned gx1 = (gx0 + 1) & (H - 1);
                    unsigned gy0 = ((unsigned)(int)y0) & (W - 1);
                    unsigned gy1 = (gy0 + 1) & (W - 1);
                    unsigned base = (unsigned)b * (unsigned)HW;
                    unsigned pos = atomicAdd(counter, 4u);
                    if (pos + 4u <= capacity) {
                        entries[pos + 0] = make_uint2(base + gx0 * W + gy0, __float_as_uint(wx0 * wy0));
                        entries[pos + 1] = make_uint2(base + gx0 * W + gy1, __float_as_uint(wx0 * wy1));
                        entries[pos + 2] = make_uint2(base + gx1 * W + gy0, __float_as_uint(wx1 * wy0));
                        entries[pos + 3] = make_uint2(base + gx1 * W + gy1, __float_as_uint(wx1 * wy1));
                    }
                }
            }
        }
    }

    // route column slots and commit with plain stores (exclusive ownership)
    #pragma unroll
    for (int m = 0; m < RB; ++m) {
        float v = 0.0f;
        #pragma unroll
        for (int k = 0; k < 7; ++k)
            v += __shfl(slot[m][k], lane - (k - 3));
        if (ownedCol)
            outb[(size_t)(r0 + m) * W + scu] = v;
    }
}

__global__ __launch_bounds__(256)
void flush_fallback(const uint2* __restrict__ entries, const unsigned* __restrict__ counter,
                    float* __restrict__ out, unsigned capacity) {
    unsigned n = *counter;
    if (n > capacity) n = capacity;
    unsigned stride = gridDim.x * blockDim.x;
    for (unsigned i = blockIdx.x * blockDim.x + threadIdx.x; i < n; i += stride) {
        uint2 e = entries[i];
        atomicAdd(out + e.x, __uint_as_float(e.y));
    }
}

extern "C" void kernel_launch(void* const* d_in, const int* in_sizes, int n_in,
                              void* d_out, int out_size, void* d_ws, size_t ws_size,
                              hipStream_t stream) {
    const float* phi = (const float*)d_in[0];
    float* out = (float*)d_out;

    unsigned* counter = (unsigned*)d_ws;
    uint2* entries = (uint2*)((char*)d_ws + 16);
    size_t capEntries = (ws_size > 16) ? (ws_size - 16) / sizeof(uint2) : 0;
    unsigned capacity = (unsigned)(capEntries > (8u << 20) ? (8u << 20) : capEntries);

    hipMemsetAsync(counter, 0, sizeof(unsigned), stream);

    int B = out_size / HW;
    int grid = B * NCH * (H / ROWSPB);      // 4 * 37 * 64 = 9472 blocks
    splat_gather8<<<grid, 256, 0, stream>>>(phi, out, counter, entries, capacity);
    flush_fallback<<<256, 256, 0, stream>>>(entries, counter, out, capacity);
}

// Round 8
// 916.015 us; speedup vs baseline: 1.0111x; 1.0111x over previous
//
#include <hip/hip_runtime.h>

// phi (B,2,H,W) f32 -> out (B,1,H,W) f32 ; splat ones with bilinear weights, wrap BC.
// Gather formulation, tent weights, RB=4 multi-row amortization (proven no-spill),
// store-only commit (exclusive ownership -> no commit atomics, no output memset),
// compile-time-pruned (t,m) pairs, wave-aggregated fallback-list counter.
constexpr int H = 2048, W = 2048;
constexpr int HW = H * W;
constexpr int OUTW = 56;                    // output cols per wave (64 lanes - 8 halo)
constexpr int NCH = (W + OUTW - 1) / OUTW;  // 37 col-chunks (last ragged)
constexpr int RB  = 4;                      // owned rows per wave (52 VGPR @ R6 -- no spill)
constexpr int WPB = 4;                      // waves per block
constexpr int ROWSPB = RB * WPB;            // 16 rows per block
constexpr int NSRC = RB + 6;                // 10 scanned source rows per wave

__global__ __launch_bounds__(256, 4)        // cap 128 VGPR; plenty for ~60 live
void splat_gather4s(const float* __restrict__ phi, float* __restrict__ out,
                    unsigned* __restrict__ counter, uint2* __restrict__ entries,
                    unsigned capacity) {
    int wid  = threadIdx.x >> 6;
    int lane = threadIdx.x & 63;

    const int rgPerImg = H / ROWSPB;        // 128
    int bid = blockIdx.x;
    int b   = bid / (NCH * rgPerImg);
    int rem = bid - b * (NCH * rgPerImg);
    int c0i = rem / rgPerImg;
    int rg  = rem - c0i * rgPerImg;
    int r0  = rg * ROWSPB + wid * RB;       // first owned row of this wave
    int c0  = c0i * OUTW;

    const float* phiB = phi + (size_t)b * 2 * HW;
    float* outb = out + (size_t)b * HW;

    int scu = c0 - 4 + lane;                // unwrapped source col of this lane
    int scw = scu & (W - 1);                // wrapped col for loads
    bool ownedCol = (lane >= 4) && (lane < 4 + OUTW) && (scu < W);

    // prefetch the NSRC candidate source rows (both displacement planes), coalesced
    float dxv[NSRC], dyv[NSRC];
    #pragma unroll
    for (int t = 0; t < NSRC; ++t) {
        int srow = (r0 + t - 3) & (H - 1);
        dxv[t] = phiB[(size_t)srow * W + scw];
        dyv[t] = phiB[(size_t)HW + (size_t)srow * W + scw];
    }

    float slot[RB][7];
    #pragma unroll
    for (int m = 0; m < RB; ++m)
        #pragma unroll
        for (int k = 0; k < 7; ++k) slot[m][k] = 0.0f;

    #pragma unroll
    for (int t = 0; t < NSRC; ++t) {
        float dx = dxv[t], dy = dyv[t];
        bool valid = (__builtin_fabsf(dx) < 3.0f) && (__builtin_fabsf(dy) < 3.0f);
        float dyM = valid ? dy : 16384.0f;   // invalid -> all col tents 0 -> list only

        // col tent weights toward offsets ko = k-3 (shared across owned rows)
        float ct[7];
        #pragma unroll
        for (int k = 0; k < 7; ++k) {
            float d = dyM - (float)(k - 3);
            ct[k] = __builtin_fmaxf(1.0f - __builtin_fabsf(d), 0.0f);
        }

        // row tents toward owned rows + rank-1 accumulate (pruned: rw==0 if |t-3-m|>=4)
        #pragma unroll
        for (int m = 0; m < RB; ++m) {
            if (t - m < 0 || t - m > 6) continue;   // compile-time DCE under unroll
            float dist = dx + (float)(t - 3 - m);   // x - (r0+m), unwrapped
            float rw = __builtin_fmaxf(1.0f - __builtin_fabsf(dist), 0.0f);
            #pragma unroll
            for (int k = 0; k < 7; ++k)
                slot[m][k] = __builtin_fmaf(rw, ct[k], slot[m][k]);
        }

        // wide-displacement fallback: this wave owns source row r0+(t-3) for t in [3,3+RB).
        // Wave-aggregated counter: ONE atomic per wave occurrence (not per lane).
        if (t >= 3 && t < 3 + RB) {
            bool need = (!valid) && ownedCol;
            unsigned long long mask = __ballot(need);
            if (mask) {
                int leader = (int)(__ffsll((long long)mask) - 1);
                int nact   = __popcll(mask);
                unsigned pos0 = 0;
                if (lane == leader) pos0 = atomicAdd(counter, 4u * (unsigned)nact);
                pos0 = __shfl(pos0, leader);
                if (need) {
                    unsigned prefix = (unsigned)__popcll(mask & ((1ull << lane) - 1ull));
                    unsigned pos = pos0 + 4u * prefix;
                    int srow = (r0 + t - 3) & (H - 1);
                    float x = (float)srow + dx;
                    float y = (float)scw + dy;
                    float x0 = floorf(x), y0 = floorf(y);
                    float wx1 = x - x0, wx0 = 1.0f - wx1;
                    float wy1 = y - y0, wy0 = 1.0f - wy1;
                    unsigned gx0 = ((unsigned)(int)x0) & (H - 1);
                    unsigned gx1 = (gx0 + 1) & (H - 1);
                    unsigned gy0 = ((unsigned)(int)y0) & (W - 1);
                    unsigned gy1 = (gy0 + 1) & (W - 1);
                    unsigned base = (unsigned)b * (unsigned)HW;
                    if (pos + 4u <= capacity) {
                        entries[pos + 0] = make_uint2(base + gx0 * W + gy0, __float_as_uint(wx0 * wy0));
                        entries[pos + 1] = make_uint2(base + gx0 * W + gy1, __float_as_uint(wx0 * wy1));
                        entries[pos + 2] = make_uint2(base + gx1 * W + gy0, __float_as_uint(wx1 * wy0));
                        entries[pos + 3] = make_uint2(base + gx1 * W + gy1, __float_as_uint(wx1 * wy1));
                    }
                }
            }
        }
    }

    // route column slots and commit with plain stores (exclusive ownership)
    #pragma unroll
    for (int m = 0; m < RB; ++m) {
        float v = 0.0f;
        #pragma unroll
        for (int k = 0; k < 7; ++k)
            v += __shfl(slot[m][k], lane - (k - 3));
        if (ownedCol)
            outb[(size_t)(r0 + m) * W + scu] = v;
    }
}

__global__ __launch_bounds__(256)
void flush_fallback(const uint2* __restrict__ entries, const unsigned* __restrict__ counter,
                    float* __restrict__ out, unsigned capacity) {
    unsigned n = *counter;
    if (n > capacity) n = capacity;
    unsigned stride = gridDim.x * blockDim.x;
    for (unsigned i = blockIdx.x * blockDim.x + threadIdx.x; i < n; i += stride) {
        uint2 e = entries[i];
        atomicAdd(out + e.x, __uint_as_float(e.y));
    }
}

extern "C" void kernel_launch(void* const* d_in, const int* in_sizes, int n_in,
                              void* d_out, int out_size, void* d_ws, size_t ws_size,
                              hipStream_t stream) {
    const float* phi = (const float*)d_in[0];
    float* out = (float*)d_out;

    unsigned* counter = (unsigned*)d_ws;
    uint2* entries = (uint2*)((char*)d_ws + 16);
    size_t capEntries = (ws_size > 16) ? (ws_size - 16) / sizeof(uint2) : 0;
    unsigned capacity = (unsigned)(capEntries > (8u << 20) ? (8u << 20) : capEntries);

    hipMemsetAsync(counter, 0, sizeof(unsigned), stream);

    int B = out_size / HW;
    int grid = B * NCH * (H / ROWSPB);      // 4 * 37 * 128 = 18944 blocks
    splat_gather4s<<<grid, 256, 0, stream>>>(phi, out, counter, entries, capacity);
    flush_fallback<<<256, 256, 0, stream>>>(entries, counter, out, capacity);
}

// Round 9
// 94.036 us; speedup vs baseline: 9.8495x; 9.7411x over previous
//
#include <hip/hip_runtime.h>

// phi (B,2,H,W) f32 -> out (B,1,H,W) f32 ; splat ones with bilinear weights, wrap BC.
// Gather formulation, tent weights, RB=4 multi-row amortization, store-only commit
// (exclusive ownership -> no commit atomics, no output memset), compile-time-pruned
// (t,m) pairs. Wide-displacement sources (|dx|>=3 or |dy|>=3, P~0.5%) are handled by:
//   main kernel: owner wave plain-stores a per-(srow,chunk) byte flag (no atomics);
//   flush kernel: re-scans flagged chunks, recomputes, scattered atomicAdds into out.
// No global counter anywhere (R7/R8 lesson: ~90K serialized same-address device
// atomics == ~900us makespan wall).
constexpr int H = 2048, W = 2048;
constexpr int HW = H * W;
constexpr int OUTW = 56;                    // output cols per wave (64 lanes - 8 halo)
constexpr int NCH = (W + OUTW - 1) / OUTW;  // 37 col-chunks (last ragged)
constexpr int RB  = 4;                      // owned rows per wave (proven no-spill)
constexpr int WPB = 4;                      // waves per block
constexpr int ROWSPB = RB * WPB;            // 16 rows per block
constexpr int NSRC = RB + 6;                // 10 scanned source rows per wave

__global__ __launch_bounds__(256)
void splat_gather4f(const float* __restrict__ phi, float* __restrict__ out,
                    unsigned char* __restrict__ flags) {
    int wid  = threadIdx.x >> 6;
    int lane = threadIdx.x & 63;

    const int rgPerImg = H / ROWSPB;        // 128
    int bid = blockIdx.x;
    int b   = bid / (NCH * rgPerImg);
    int rem = bid - b * (NCH * rgPerImg);
    int c0i = rem / rgPerImg;
    int rg  = rem - c0i * rgPerImg;
    int r0  = rg * ROWSPB + wid * RB;       // first owned row of this wave
    int c0  = c0i * OUTW;

    const float* phiB = phi + (size_t)b * 2 * HW;
    float* outb = out + (size_t)b * HW;

    int scu = c0 - 4 + lane;                // unwrapped source col of this lane
    int scw = scu & (W - 1);                // wrapped col for loads
    bool ownedCol = (lane >= 4) && (lane < 4 + OUTW) && (scu < W);

    // prefetch the NSRC candidate source rows (both displacement planes), coalesced
    float dxv[NSRC], dyv[NSRC];
    #pragma unroll
    for (int t = 0; t < NSRC; ++t) {
        int srow = (r0 + t - 3) & (H - 1);
        dxv[t] = phiB[(size_t)srow * W + scw];
        dyv[t] = phiB[(size_t)HW + (size_t)srow * W + scw];
    }

    float slot[RB][7];
    #pragma unroll
    for (int m = 0; m < RB; ++m)
        #pragma unroll
        for (int k = 0; k < 7; ++k) slot[m][k] = 0.0f;

    #pragma unroll
    for (int t = 0; t < NSRC; ++t) {
        float dx = dxv[t], dy = dyv[t];
        bool valid = (__builtin_fabsf(dx) < 3.0f) && (__builtin_fabsf(dy) < 3.0f);
        float dyM = valid ? dy : 16384.0f;   // invalid -> all col tents 0 -> flush only

        // col tent weights toward offsets ko = k-3 (shared across owned rows)
        float ct[7];
        #pragma unroll
        for (int k = 0; k < 7; ++k) {
            float d = dyM - (float)(k - 3);
            ct[k] = __builtin_fmaxf(1.0f - __builtin_fabsf(d), 0.0f);
        }

        // row tents toward owned rows + rank-1 accumulate (pruned: rw==0 if |t-3-m|>=4)
        #pragma unroll
        for (int m = 0; m < RB; ++m) {
            if (t - m < 0 || t - m > 6) continue;   // compile-time DCE under unroll
            float dist = dx + (float)(t - 3 - m);   // x - (r0+m), unwrapped
            float rw = __builtin_fmaxf(1.0f - __builtin_fabsf(dist), 0.0f);
            #pragma unroll
            for (int k = 0; k < 7; ++k)
                slot[m][k] = __builtin_fmaf(rw, ct[k], slot[m][k]);
        }

        // flag this wave's owned source rows (t in [3,3+RB)): plain byte store, no atomics
        if (t >= 3 && t < 3 + RB) {
            bool need = (!valid) && ownedCol;
            unsigned long long mask = __ballot(need);
            if (lane == 0) {
                int srow = (r0 + t - 3) & (H - 1);
                flags[(size_t)(b * H + srow) * NCH + c0i] = (mask != 0ull) ? 1 : 0;
            }
        }
    }

    // route column slots and commit with plain stores (exclusive ownership)
    #pragma unroll
    for (int m = 0; m < RB; ++m) {
        float v = 0.0f;
        #pragma unroll
        for (int k = 0; k < 7; ++k)
            v += __shfl(slot[m][k], lane - (k - 3));
        if (ownedCol)
            outb[(size_t)(r0 + m) * W + scu] = v;
    }
}

// Re-scan flagged (srow, chunk) pairs; scattered atomics for the rare wide sources.
__global__ __launch_bounds__(256)
void flush_flagged(const float* __restrict__ phi, const unsigned char* __restrict__ flags,
                   float* __restrict__ out) {
    int wid  = threadIdx.x >> 6;
    int lane = threadIdx.x & 63;
    long long chunk = (long long)blockIdx.x * WPB + wid;   // [0, B*H*NCH)

    if (!flags[chunk]) return;

    int c0i = (int)(chunk % NCH);
    long long bs = chunk / NCH;
    int srow = (int)(bs & (H - 1));
    int b    = (int)(bs >> 11);            // H = 2048

    int col = c0i * OUTW + lane;           // lanes [0,56) own cols of this chunk
    if (lane >= OUTW || col >= W) return;

    const float* phiB = phi + (size_t)b * 2 * HW;
    float dx = phiB[(size_t)srow * W + col];
    float dy = phiB[(size_t)HW + (size_t)srow * W + col];
    if ((__builtin_fabsf(dx) < 3.0f) && (__builtin_fabsf(dy) < 3.0f)) return;

    float* outb = out + (size_t)b * HW;
    float x = (float)srow + dx;
    float y = (float)col + dy;
    float x0 = floorf(x), y0 = floorf(y);
    float wx1 = x - x0, wx0 = 1.0f - wx1;
    float wy1 = y - y0, wy0 = 1.0f - wy1;
    int gx0 = ((int)x0) & (H - 1);
    int gx1 = (gx0 + 1) & (H - 1);
    int gy0 = ((int)y0) & (W - 1);
    int gy1 = (gy0 + 1) & (W - 1);
    atomicAdd(outb + (size_t)gx0 * W + gy0, wx0 * wy0);
    atomicAdd(outb + (size_t)gx0 * W + gy1, wx0 * wy1);
    atomicAdd(outb + (size_t)gx1 * W + gy0, wx1 * wy0);
    atomicAdd(outb + (size_t)gx1 * W + gy1, wx1 * wy1);
}

extern "C" void kernel_launch(void* const* d_in, const int* in_sizes, int n_in,
                              void* d_out, int out_size, void* d_ws, size_t ws_size,
                              hipStream_t stream) {
    const float* phi = (const float*)d_in[0];
    float* out = (float*)d_out;
    unsigned char* flags = (unsigned char*)d_ws;   // B*H*NCH bytes, written unconditionally

    int B = out_size / HW;
    int grid = B * NCH * (H / ROWSPB);             // 4 * 37 * 128 = 18944 blocks
    splat_gather4f<<<grid, 256, 0, stream>>>(phi, out, flags);

    long long nChunks = (long long)B * H * NCH;    // 303,104
    int grid2 = (int)(nChunks / WPB);              // 75,776 blocks (divides exactly)
    flush_flagged<<<grid2, 256, 0, stream>>>(phi, flags, out);
}